// Round 1
// baseline (1155.679 us; speedup 1.0000x reference)
//
#include <hip/hip_runtime.h>

typedef unsigned short u16;
typedef __attribute__((ext_vector_type(8))) short bf16x8;
typedef __attribute__((ext_vector_type(8))) unsigned short u16x8;
typedef __attribute__((ext_vector_type(4))) float f32x4;

__device__ __forceinline__ u16 f2bf(float f) {
  unsigned u = __builtin_bit_cast(unsigned, f);
  u += 0x7fffu + ((u >> 16) & 1u);
  return (u16)(u >> 16);
}
__device__ __forceinline__ float bf2f(u16 h) {
  unsigned u = ((unsigned)h) << 16;
  return __builtin_bit_cast(float, u);
}

#define NB 2048
#define NF 100
#define NE 64
#define NO 256
#define OCH 64
#define EMB_ST 68
#define EMBT_ST 136
#define G_ST 104
#define AW_ST 136
#define NIT 22

// ---------------- prep: M[o][e] = 0.0625 * sum_k query[o,k]*Wb[k,e] ----------------
__global__ void k_prep_M(const float* __restrict__ wb, const float* __restrict__ q,
                         u16* __restrict__ mt) {
  int idx = blockIdx.x * 256 + threadIdx.x;   // 16384 = 256*64
  int o = idx >> 6, e = idx & 63;
  float s = 0.f;
  for (int k = 0; k < 64; ++k) s = fmaf(q[o * 64 + k], wb[k * 64 + e], s);
  mt[idx] = f2bf(s * 0.0625f);   // folds DK^-0.5 (0.125) and (alpha-1) (0.5)
}

// ---------------- f32 -> bf16 conversion ----------------
__global__ void k_cvt(const float* __restrict__ in, u16* __restrict__ out, int n) {
  int i4 = (blockIdx.x * 256 + threadIdx.x) * 4;
  if (i4 >= n) return;
  float4 v = *(const float4*)(in + i4);
  ushort4 o;
  o.x = f2bf(v.x); o.y = f2bf(v.y); o.z = f2bf(v.z); o.w = f2bf(v.w);
  *(ushort4*)(out + i4) = o;
}

// ---------------- fused gather + gates GEMM + entmax + arm GEMM + expm1 ----------------
__global__ __launch_bounds__(256) void k_mega(
    const int* __restrict__ ids, const float* __restrict__ vals,
    const float* __restrict__ etab, const u16* __restrict__ mt,
    const float* __restrict__ att, u16* __restrict__ tbuf) {
  __shared__ u16 s_emb[112][EMB_ST];     // [f][e], rows 100..111 zero
  __shared__ u16 s_embT[64][EMBT_ST];    // [e][f], cols 100..135 zero
  __shared__ u16 s_gates[64][G_ST];      // x = gates*(alpha-1), bf16
  __shared__ u16 s_aw[64][AW_ST];        // p_norm * att, cols 100..135 zero

  const int tid = threadIdx.x;
  const int lane = tid & 63;
  const int wid = tid >> 6;
  const int b = blockIdx.x;
  const int obase = blockIdx.y * OCH;

  // phase 0: gather emb = emb_table[ids]*clip(v)
  for (int f = wid; f < NF; f += 4) {
    int id = ids[b * NF + f];
    float v = vals[b * NF + f];
    v = fminf(fmaxf(v, 0.001f), 1.0f);
    float ev = etab[(size_t)id * NE + lane] * v;
    u16 bf = f2bf(ev);
    s_emb[f][lane] = bf;
    s_embT[lane][f] = bf;
  }
  for (int i = tid; i < 12 * 64; i += 256) s_emb[100 + (i >> 6)][i & 63] = 0;
  for (int i = tid; i < 64 * 36; i += 256) s_embT[i / 36][100 + i % 36] = 0;

  // per-wave A fragments of M (o-tile = wid)
  bf16x8 amt[2];
#pragma unroll
  for (int kh = 0; kh < 2; ++kh)
    amt[kh] = *(const bf16x8*)(mt + ((obase + wid * 16 + (lane & 15)) * 64 +
                                     kh * 32 + ((lane >> 4) * 8)));
  __syncthreads();

  // phase 1: gates[o][f] = M[o,:]·emb[f,:]  (K=64, 2 MFMA per f-tile)
#pragma unroll
  for (int ft = 0; ft < 7; ++ft) {
    f32x4 acc = {0.f, 0.f, 0.f, 0.f};
#pragma unroll
    for (int kh = 0; kh < 2; ++kh) {
      bf16x8 bfr = *(const bf16x8*)&s_emb[ft * 16 + (lane & 15)][kh * 32 + ((lane >> 4) * 8)];
      acc = __builtin_amdgcn_mfma_f32_16x16x32_bf16(amt[kh], bfr, acc, 0, 0, 0);
    }
    int fc = ft * 16 + (lane & 15);
    if (fc < NF) {
#pragma unroll
      for (int i = 0; i < 4; ++i)
        s_gates[wid * 16 + ((lane >> 4) * 4) + i][fc] = f2bf(acc[i]);
    }
  }
  __syncthreads();

  // phase 2: entmax (alpha=1.5) via bisection; quad (4 lanes) per o-row
  {
    const int q = tid & 3;
    const int r = tid >> 2;
    const int og = obase + r;
    float x[25];
#pragma unroll
    for (int j = 0; j < 25; ++j) x[j] = bf2f(s_gates[r][q * 25 + j]);
    float mx = x[0];
#pragma unroll
    for (int j = 1; j < 25; ++j) mx = fmaxf(mx, x[j]);
    mx = fmaxf(mx, __shfl_xor(mx, 1));
    mx = fmaxf(mx, __shfl_xor(mx, 2));
    float tau = mx - 1.0f, dm = 0.9f;   // tau_hi - tau_lo = 1 - (1/100)^0.5
    for (int it = 0; it < NIT; ++it) {
      dm *= 0.5f;
      float tm = tau + dm;
      float s = 0.f;
#pragma unroll
      for (int j = 0; j < 25; ++j) { float d = fmaxf(x[j] - tm, 0.f); s = fmaf(d, d, s); }
      s += __shfl_xor(s, 1);
      s += __shfl_xor(s, 2);
      if (s >= 1.0f) tau = tm;
    }
    float s = 0.f;
#pragma unroll
    for (int j = 0; j < 25; ++j) {
      float d = fmaxf(x[j] - tau, 0.f);
      float p = d * d;
      x[j] = p;
      s += p;
    }
    s += __shfl_xor(s, 1);
    s += __shfl_xor(s, 2);
    float rs = 1.0f / s;
#pragma unroll
    for (int j = 0; j < 25; ++j) {
      int f = q * 25 + j;
      s_aw[r][f] = f2bf(x[j] * rs * att[og * NF + f]);
    }
#pragma unroll
    for (int j = 0; j < 9; ++j) s_aw[r][100 + q * 9 + j] = 0;
  }
  __syncthreads();

  // phase 3: arm[o][e] = sum_f aw[o][f]*emb[f][e];  store t = expm1(arm)
  f32x4 acc[4] = {};
#pragma unroll
  for (int h = 0; h < 4; ++h) {
    bf16x8 afr = *(const bf16x8*)&s_aw[wid * 16 + (lane & 15)][h * 32 + ((lane >> 4) * 8)];
#pragma unroll
    for (int et = 0; et < 4; ++et) {
      bf16x8 bfr = *(const bf16x8*)&s_embT[et * 16 + (lane & 15)][h * 32 + ((lane >> 4) * 8)];
      acc[et] = __builtin_amdgcn_mfma_f32_16x16x32_bf16(afr, bfr, acc[et], 0, 0, 0);
    }
  }
  size_t orow = (size_t)b * NO + obase + wid * 16 + ((lane >> 4) * 4);
#pragma unroll
  for (int et = 0; et < 4; ++et) {
    int e = et * 16 + (lane & 15);
#pragma unroll
    for (int i = 0; i < 4; ++i)
      tbuf[(orow + i) * 64 + e] = f2bf(expm1f(acc[et][i]));
  }
}

// ---------------- per-o BN stats over (b,e):  scl=g*inv, bia=be-g*inv*mean ----------------
__global__ void k_stats_o(const u16* __restrict__ t, const float* __restrict__ g,
                          const float* __restrict__ be, float* __restrict__ scl,
                          float* __restrict__ bia) {
  int tid = threadIdx.x;
  int o = blockIdx.x;
  int e = tid & 63, gq = tid >> 6;
  float s = 0.f, s2 = 0.f;
  for (int b = gq; b < NB; b += 4) {
    float v = bf2f(t[((size_t)b * NO + o) * 64 + e]);
    s += v;
    s2 = fmaf(v, v, s2);
  }
  __shared__ float red[2][256];
  red[0][tid] = s; red[1][tid] = s2;
  __syncthreads();
  for (int st = 128; st >= 1; st >>= 1) {
    if (tid < st) { red[0][tid] += red[0][tid + st]; red[1][tid] += red[1][tid + st]; }
    __syncthreads();
  }
  if (tid == 0) {
    float N = (float)(NB * 64);
    float m = red[0][0] / N;
    float var = red[1][0] / N - m * m;
    float inv = rsqrtf(var + 1e-5f);
    scl[o] = g[o] * inv;
    bia[o] = be[o] - g[o] * inv * m;
  }
}

// ---------------- apply arm-BN: a0 = bf16(t*scl[o] + bia[o]) ----------------
__global__ void k_applyA0(const u16* __restrict__ t, const float* __restrict__ scl,
                          const float* __restrict__ bia, u16* __restrict__ a0) {
  size_t i8 = ((size_t)blockIdx.x * 256 + threadIdx.x) * 8;
  int o = (int)((i8 >> 6) & 255);
  u16x8 tv = *(const u16x8*)(t + i8);
  float sc = scl[o], bi = bia[o];
  u16x8 ov;
#pragma unroll
  for (int j = 0; j < 8; ++j) ov[j] = f2bf(fmaf(bf2f(tv[j]), sc, bi));
  *(u16x8*)(a0 + i8) = ov;
}

// ---------------- bf16 GEMM, C[m][n] = sum_k A[m][k]*B[n][k] (B^T layout) ----------------
__global__ __launch_bounds__(256) void k_gemm(const u16* __restrict__ A,
                                              const u16* __restrict__ B,
                                              float* __restrict__ C,
                                              int M, int N, int K, int ksz) {
  __shared__ u16 sA[128][72];
  __shared__ u16 sB[128][72];
  const int tid = threadIdx.x, lane = tid & 63, wid = tid >> 6;
  const int wr = wid >> 1, wc = wid & 1;
  const int m0 = blockIdx.x * 128, n0 = blockIdx.y * 128;
  const int k0 = blockIdx.z * ksz;
  C += (size_t)blockIdx.z * ((size_t)M * N);
  f32x4 acc[4][4];
#pragma unroll
  for (int mi = 0; mi < 4; ++mi)
#pragma unroll
    for (int ni = 0; ni < 4; ++ni) acc[mi][ni] = (f32x4){0.f, 0.f, 0.f, 0.f};

  const int row_s = tid >> 3;    // 0..31
  const int off_s = tid & 7;     // 16B chunk within 128B row
  const u16* gA = A + (size_t)(m0 + row_s) * K + k0 + off_s * 8;
  const u16* gB = B + (size_t)(n0 + row_s) * K + k0 + off_s * 8;
  const int nkt = ksz / 64;
  for (int kt = 0; kt < nkt; ++kt) {
    uint4 ra[4], rb[4];
#pragma unroll
    for (int i = 0; i < 4; ++i) {
      ra[i] = *(const uint4*)(gA + (size_t)i * 32 * K);
      rb[i] = *(const uint4*)(gB + (size_t)i * 32 * K);
    }
    gA += 64; gB += 64;
    __syncthreads();
#pragma unroll
    for (int i = 0; i < 4; ++i) {
      *(uint4*)&sA[i * 32 + row_s][off_s * 8] = ra[i];
      *(uint4*)&sB[i * 32 + row_s][off_s * 8] = rb[i];
    }
    __syncthreads();
#pragma unroll
    for (int kh = 0; kh < 2; ++kh) {
      bf16x8 af[4], bfv[4];
#pragma unroll
      for (int i = 0; i < 4; ++i) {
        af[i]  = *(const bf16x8*)&sA[wr * 64 + i * 16 + (lane & 15)][kh * 32 + ((lane >> 4) * 8)];
        bfv[i] = *(const bf16x8*)&sB[wc * 64 + i * 16 + (lane & 15)][kh * 32 + ((lane >> 4) * 8)];
      }
#pragma unroll
      for (int mi = 0; mi < 4; ++mi)
#pragma unroll
        for (int ni = 0; ni < 4; ++ni)
          acc[mi][ni] = __builtin_amdgcn_mfma_f32_16x16x32_bf16(af[mi], bfv[ni], acc[mi][ni], 0, 0, 0);
    }
  }
#pragma unroll
  for (int mi = 0; mi < 4; ++mi) {
    int m = m0 + wr * 64 + mi * 16 + ((lane >> 4) * 4);
#pragma unroll
    for (int ni = 0; ni < 4; ++ni) {
      int n = n0 + wc * 64 + ni * 16 + (lane & 15);
#pragma unroll
      for (int i = 0; i < 4; ++i) C[(size_t)(m + i) * N + n] = acc[mi][ni][i];
    }
  }
}

// ---------------- per-column BN stats over batch (optionally summing two partials) ----------------
__global__ void k_stats_cols(const float* __restrict__ c0, const float* __restrict__ c1,
                             const float* __restrict__ g, const float* __restrict__ be,
                             float* __restrict__ scl, float* __restrict__ bia,
                             int rows, int cols) {
  int tid = threadIdx.x;
  int col = blockIdx.x * 64 + (tid & 63);
  int gq = tid >> 6;
  float s = 0.f, s2 = 0.f;
  for (int r = gq; r < rows; r += 4) {
    float v = c0[(size_t)r * cols + col];
    if (c1) v += c1[(size_t)r * cols + col];
    s += v;
    s2 = fmaf(v, v, s2);
  }
  __shared__ float red[2][256];
  red[0][tid] = s; red[1][tid] = s2;
  __syncthreads();
  if (tid < 64) {
    s  = red[0][tid] + red[0][tid + 64] + red[0][tid + 128] + red[0][tid + 192];
    s2 = red[1][tid] + red[1][tid + 64] + red[1][tid + 128] + red[1][tid + 192];
    float m = s / rows;
    float var = s2 / rows - m * m;
    float inv = rsqrtf(var + 1e-5f);
    scl[col] = g[col] * inv;
    bia[col] = be[col] - g[col] * inv * m;
  }
}

// ---------------- a1 = bf16(relu((c0+c1)*scl + bia)) ----------------
__global__ void k_applyA1(const float* __restrict__ c0, const float* __restrict__ c1,
                          const float* __restrict__ scl, const float* __restrict__ bia,
                          u16* __restrict__ a1) {
  size_t i4 = ((size_t)blockIdx.x * 256 + threadIdx.x) * 4;
  int n = (int)(i4 & 1023);
  float4 v0 = *(const float4*)(c0 + i4);
  float4 v1 = *(const float4*)(c1 + i4);
  float vv[4] = {v0.x + v1.x, v0.y + v1.y, v0.z + v1.z, v0.w + v1.w};
  ushort4 o;
  o.x = f2bf(fmaxf(fmaf(vv[0], scl[n + 0], bia[n + 0]), 0.f));
  o.y = f2bf(fmaxf(fmaf(vv[1], scl[n + 1], bia[n + 1]), 0.f));
  o.z = f2bf(fmaxf(fmaf(vv[2], scl[n + 2], bia[n + 2]), 0.f));
  o.w = f2bf(fmaxf(fmaf(vv[3], scl[n + 3], bia[n + 3]), 0.f));
  *(ushort4*)(a1 + i4) = o;
}

// ---------------- y[b] = out_b + sum_n relu(h1*scl+bia)*out_w[n] ----------------
__global__ void k_final(const float* __restrict__ h1, const float* __restrict__ scl,
                        const float* __restrict__ bia, const float* __restrict__ ow,
                        const float* __restrict__ ob, float* __restrict__ y) {
  int lane = threadIdx.x & 63, wid = threadIdx.x >> 6;
  int row = blockIdx.x * 4 + wid;
  const float* hr = h1 + (size_t)row * 1024;
  float part = 0.f;
#pragma unroll
  for (int j = 0; j < 16; ++j) {
    int n = j * 64 + lane;
    float v = fmaf(hr[n], scl[n], bia[n]);
    v = fmaxf(v, 0.f);
    part = fmaf(v, ow[n], part);
  }
#pragma unroll
  for (int off = 32; off >= 1; off >>= 1) part += __shfl_xor(part, off);
  if (lane == 0) y[row] = part + ob[0];
}

extern "C" void kernel_launch(void* const* d_in, const int* in_sizes, int n_in,
                              void* d_out, int out_size, void* d_ws, size_t ws_size,
                              hipStream_t stream) {
  const int*   ids   = (const int*)d_in[0];
  const float* vals  = (const float*)d_in[1];
  const float* etab  = (const float*)d_in[2];
  const float* wb    = (const float*)d_in[3];
  const float* query = (const float*)d_in[4];
  const float* att   = (const float*)d_in[5];
  const float* bng   = (const float*)d_in[6];
  const float* bnb   = (const float*)d_in[7];
  const float* w0    = (const float*)d_in[8];
  const float* g0    = (const float*)d_in[10];
  const float* be0   = (const float*)d_in[11];
  const float* w1    = (const float*)d_in[12];
  const float* g1    = (const float*)d_in[14];
  const float* be1   = (const float*)d_in[15];
  const float* outw  = (const float*)d_in[16];
  const float* outb  = (const float*)d_in[17];
  float* y = (float*)d_out;

  char* ws = (char*)d_ws;
  u16*   mt   = (u16*)(ws + 0);
  u16*   w0bf = (u16*)(ws + 32768ull);
  u16*   w1bf = (u16*)(ws + 33587200ull);
  u16*   tbuf = (u16*)(ws + 35684352ull);
  u16*   a0   = (u16*)(ws + 102793216ull);
  float* c01  = (float*)(ws + 169902080ull);
  u16*   a1   = (u16*)(ws + 186679296ull);
  float* h1   = (float*)(ws + 190873600ull);
  float* sclA = (float*)(ws + 199262208ull);
  float* biaA = (float*)(ws + 199263232ull);
  float* scl1 = (float*)(ws + 199264256ull);
  float* bia1 = (float*)(ws + 199268352ull);
  float* scl2 = (float*)(ws + 199272448ull);
  float* bia2 = (float*)(ws + 199276544ull);

  k_prep_M<<<64, 256, 0, stream>>>(wb, query, mt);
  k_cvt<<<16384, 256, 0, stream>>>(w0, w0bf, 1024 * 16384);
  k_cvt<<<1024, 256, 0, stream>>>(w1, w1bf, 1024 * 1024);
  k_mega<<<dim3(2048, 4), 256, 0, stream>>>(ids, vals, etab, mt, att, tbuf);
  k_stats_o<<<256, 256, 0, stream>>>(tbuf, bng, bnb, sclA, biaA);
  k_applyA0<<<16384, 256, 0, stream>>>(tbuf, sclA, biaA, a0);
  k_gemm<<<dim3(16, 8, 2), 256, 0, stream>>>(a0, w0bf, c01, 2048, 1024, 16384, 8192);
  k_stats_cols<<<16, 256, 0, stream>>>(c01, c01 + 2048 * 1024, g0, be0, scl1, bia1, 2048, 1024);
  k_applyA1<<<2048, 256, 0, stream>>>(c01, c01 + 2048 * 1024, scl1, bia1, a1);
  k_gemm<<<dim3(16, 8, 1), 256, 0, stream>>>(a1, w1bf, h1, 2048, 1024, 1024, 1024);
  k_stats_cols<<<16, 256, 0, stream>>>(h1, nullptr, g1, be1, scl2, bia2, 2048, 1024);
  k_final<<<512, 256, 0, stream>>>(h1, scl2, bia2, outw, outb, y);
}

// Round 2
// 1114.759 us; speedup vs baseline: 1.0367x; 1.0367x over previous
//
#include <hip/hip_runtime.h>

typedef unsigned short u16;
typedef __attribute__((ext_vector_type(8))) short bf16x8;
typedef __attribute__((ext_vector_type(8))) unsigned short u16x8;
typedef __attribute__((ext_vector_type(4))) float f32x4;

__device__ __forceinline__ u16 f2bf(float f) {
  unsigned u = __builtin_bit_cast(unsigned, f);
  u += 0x7fffu + ((u >> 16) & 1u);
  return (u16)(u >> 16);
}
__device__ __forceinline__ float bf2f(u16 h) {
  unsigned u = ((unsigned)h) << 16;
  return __builtin_bit_cast(float, u);
}

#define NB 2048
#define NF 100
#define NE 64
#define NO 256
#define OCH 64
#define EMB_ST 68
#define EMBT_ST 136
#define G_ST 104
#define AW_ST 136
#define NIT 22

// ---------------- prep: M[o][e] = 0.0625 * sum_k query[o,k]*Wb[k,e] ----------------
__global__ void k_prep_M(const float* __restrict__ wb, const float* __restrict__ q,
                         u16* __restrict__ mt) {
  int idx = blockIdx.x * 256 + threadIdx.x;   // 16384 = 256*64
  int o = idx >> 6, e = idx & 63;
  float s = 0.f;
  for (int k = 0; k < 64; ++k) s = fmaf(q[o * 64 + k], wb[k * 64 + e], s);
  mt[idx] = f2bf(s * 0.0625f);   // folds DK^-0.5 (0.125) and (alpha-1) (0.5)
}

// ---------------- f32 -> bf16 conversion ----------------
__global__ void k_cvt(const float* __restrict__ in, u16* __restrict__ out, int n) {
  int i4 = (blockIdx.x * 256 + threadIdx.x) * 4;
  if (i4 >= n) return;
  float4 v = *(const float4*)(in + i4);
  ushort4 o;
  o.x = f2bf(v.x); o.y = f2bf(v.y); o.z = f2bf(v.z); o.w = f2bf(v.w);
  *(ushort4*)(out + i4) = o;
}

// ---------------- fused gather + gates GEMM + entmax + arm GEMM + expm1 ----------------
__global__ __launch_bounds__(256) void k_mega(
    const int* __restrict__ ids, const float* __restrict__ vals,
    const float* __restrict__ etab, const u16* __restrict__ mt,
    const float* __restrict__ att, u16* __restrict__ tbuf) {
  __shared__ u16 s_emb[112][EMB_ST];     // [f][e], rows 100..111 zero
  __shared__ u16 s_embT[64][EMBT_ST];    // [e][f], cols 100..135 zero
  __shared__ u16 s_gates[64][G_ST];      // x = gates*(alpha-1), bf16
  __shared__ u16 s_aw[64][AW_ST];        // p_norm * att, cols 100..135 zero

  const int tid = threadIdx.x;
  const int lane = tid & 63;
  const int wid = tid >> 6;
  const int b = blockIdx.x;
  const int obase = blockIdx.y * OCH;

  // phase 0: gather emb = emb_table[ids]*clip(v)
  for (int f = wid; f < NF; f += 4) {
    int id = ids[b * NF + f];
    float v = vals[b * NF + f];
    v = fminf(fmaxf(v, 0.001f), 1.0f);
    float ev = etab[(size_t)id * NE + lane] * v;
    u16 bf = f2bf(ev);
    s_emb[f][lane] = bf;
    s_embT[lane][f] = bf;
  }
  for (int i = tid; i < 12 * 64; i += 256) s_emb[100 + (i >> 6)][i & 63] = 0;
  for (int i = tid; i < 64 * 36; i += 256) s_embT[i / 36][100 + i % 36] = 0;

  // per-wave A fragments of M (o-tile = wid)
  bf16x8 amt[2];
#pragma unroll
  for (int kh = 0; kh < 2; ++kh)
    amt[kh] = *(const bf16x8*)(mt + ((obase + wid * 16 + (lane & 15)) * 64 +
                                     kh * 32 + ((lane >> 4) * 8)));
  __syncthreads();

  // phase 1: gates[o][f] = M[o,:]·emb[f,:]  (K=64, 2 MFMA per f-tile)
#pragma unroll
  for (int ft = 0; ft < 7; ++ft) {
    f32x4 acc = {0.f, 0.f, 0.f, 0.f};
#pragma unroll
    for (int kh = 0; kh < 2; ++kh) {
      bf16x8 bfr = *(const bf16x8*)&s_emb[ft * 16 + (lane & 15)][kh * 32 + ((lane >> 4) * 8)];
      acc = __builtin_amdgcn_mfma_f32_16x16x32_bf16(amt[kh], bfr, acc, 0, 0, 0);
    }
    int fc = ft * 16 + (lane & 15);
    if (fc < NF) {
#pragma unroll
      for (int i = 0; i < 4; ++i)
        s_gates[wid * 16 + ((lane >> 4) * 4) + i][fc] = f2bf(acc[i]);
    }
  }
  __syncthreads();

  // phase 2: entmax (alpha=1.5) via bisection; quad (4 lanes) per o-row
  {
    const int q = tid & 3;
    const int r = tid >> 2;
    const int og = obase + r;
    float x[25];
#pragma unroll
    for (int j = 0; j < 25; ++j) x[j] = bf2f(s_gates[r][q * 25 + j]);
    float mx = x[0];
#pragma unroll
    for (int j = 1; j < 25; ++j) mx = fmaxf(mx, x[j]);
    mx = fmaxf(mx, __shfl_xor(mx, 1));
    mx = fmaxf(mx, __shfl_xor(mx, 2));
    float tau = mx - 1.0f, dm = 0.9f;   // tau_hi - tau_lo = 1 - (1/100)^0.5
    for (int it = 0; it < NIT; ++it) {
      dm *= 0.5f;
      float tm = tau + dm;
      float s = 0.f;
#pragma unroll
      for (int j = 0; j < 25; ++j) { float d = fmaxf(x[j] - tm, 0.f); s = fmaf(d, d, s); }
      s += __shfl_xor(s, 1);
      s += __shfl_xor(s, 2);
      if (s >= 1.0f) tau = tm;
    }
    float s = 0.f;
#pragma unroll
    for (int j = 0; j < 25; ++j) {
      float d = fmaxf(x[j] - tau, 0.f);
      float p = d * d;
      x[j] = p;
      s += p;
    }
    s += __shfl_xor(s, 1);
    s += __shfl_xor(s, 2);
    float rs = 1.0f / s;
#pragma unroll
    for (int j = 0; j < 25; ++j) {
      int f = q * 25 + j;
      s_aw[r][f] = f2bf(x[j] * rs * att[og * NF + f]);
    }
#pragma unroll
    for (int j = 0; j < 9; ++j) s_aw[r][100 + q * 9 + j] = 0;
  }
  __syncthreads();

  // phase 3: arm[o][e] = sum_f aw[o][f]*emb[f][e];  store t = expm1(arm)
  f32x4 acc[4] = {};
#pragma unroll
  for (int h = 0; h < 4; ++h) {
    bf16x8 afr = *(const bf16x8*)&s_aw[wid * 16 + (lane & 15)][h * 32 + ((lane >> 4) * 8)];
#pragma unroll
    for (int et = 0; et < 4; ++et) {
      bf16x8 bfr = *(const bf16x8*)&s_embT[et * 16 + (lane & 15)][h * 32 + ((lane >> 4) * 8)];
      acc[et] = __builtin_amdgcn_mfma_f32_16x16x32_bf16(afr, bfr, acc[et], 0, 0, 0);
    }
  }
  size_t orow = (size_t)b * NO + obase + wid * 16 + ((lane >> 4) * 4);
#pragma unroll
  for (int et = 0; et < 4; ++et) {
    int e = et * 16 + (lane & 15);
#pragma unroll
    for (int i = 0; i < 4; ++i)
      tbuf[(orow + i) * 64 + e] = f2bf(expm1f(acc[et][i]));
  }
}

// ---------------- per-o BN stats over (b,e):  scl=g*inv, bia=be-g*inv*mean ----------------
__global__ void k_stats_o(const u16* __restrict__ t, const float* __restrict__ g,
                          const float* __restrict__ be, float* __restrict__ scl,
                          float* __restrict__ bia) {
  int tid = threadIdx.x;
  int o = blockIdx.x;
  int e = tid & 63, gq = tid >> 6;
  float s = 0.f, s2 = 0.f;
  for (int b = gq; b < NB; b += 4) {
    float v = bf2f(t[((size_t)b * NO + o) * 64 + e]);
    s += v;
    s2 = fmaf(v, v, s2);
  }
  __shared__ float red[2][256];
  red[0][tid] = s; red[1][tid] = s2;
  __syncthreads();
  for (int st = 128; st >= 1; st >>= 1) {
    if (tid < st) { red[0][tid] += red[0][tid + st]; red[1][tid] += red[1][tid + st]; }
    __syncthreads();
  }
  if (tid == 0) {
    float N = (float)(NB * 64);
    float m = red[0][0] / N;
    float var = red[1][0] / N - m * m;
    float inv = rsqrtf(var + 1e-5f);
    scl[o] = g[o] * inv;
    bia[o] = be[o] - g[o] * inv * m;
  }
}

// ---------------- apply arm-BN: a0 = bf16(t*scl[o] + bia[o]) ----------------
__global__ void k_applyA0(const u16* __restrict__ t, const float* __restrict__ scl,
                          const float* __restrict__ bia, u16* __restrict__ a0) {
  size_t i8 = ((size_t)blockIdx.x * 256 + threadIdx.x) * 8;
  int o = (int)((i8 >> 6) & 255);
  u16x8 tv = *(const u16x8*)(t + i8);
  float sc = scl[o], bi = bia[o];
  u16x8 ov;
#pragma unroll
  for (int j = 0; j < 8; ++j) ov[j] = f2bf(fmaf(bf2f(tv[j]), sc, bi));
  *(u16x8*)(a0 + i8) = ov;
}

// ---------------- bf16 GEMM, C[m][n] = sum_k A[m][k]*B[n][k] (B^T layout), split-K ----------------
__global__ __launch_bounds__(256) void k_gemm(const u16* __restrict__ A,
                                              const u16* __restrict__ B,
                                              float* __restrict__ C,
                                              int M, int N, int K, int ksz) {
  __shared__ u16 sA[128][72];
  __shared__ u16 sB[128][72];
  const int tid = threadIdx.x, lane = tid & 63, wid = tid >> 6;
  const int wr = wid >> 1, wc = wid & 1;
  const int m0 = blockIdx.x * 128, n0 = blockIdx.y * 128;
  const int k0 = blockIdx.z * ksz;
  C += (size_t)blockIdx.z * ((size_t)M * N);
  f32x4 acc[4][4];
#pragma unroll
  for (int mi = 0; mi < 4; ++mi)
#pragma unroll
    for (int ni = 0; ni < 4; ++ni) acc[mi][ni] = (f32x4){0.f, 0.f, 0.f, 0.f};

  const int row_s = tid >> 3;    // 0..31
  const int off_s = tid & 7;     // 16B chunk within 128B row
  const u16* gA = A + (size_t)(m0 + row_s) * K + k0 + off_s * 8;
  const u16* gB = B + (size_t)(n0 + row_s) * K + k0 + off_s * 8;
  const int nkt = ksz / 64;
  for (int kt = 0; kt < nkt; ++kt) {
    uint4 ra[4], rb[4];
#pragma unroll
    for (int i = 0; i < 4; ++i) {
      ra[i] = *(const uint4*)(gA + (size_t)i * 32 * K);
      rb[i] = *(const uint4*)(gB + (size_t)i * 32 * K);
    }
    gA += 64; gB += 64;
    __syncthreads();
#pragma unroll
    for (int i = 0; i < 4; ++i) {
      *(uint4*)&sA[i * 32 + row_s][off_s * 8] = ra[i];
      *(uint4*)&sB[i * 32 + row_s][off_s * 8] = rb[i];
    }
    __syncthreads();
#pragma unroll
    for (int kh = 0; kh < 2; ++kh) {
      bf16x8 af[4], bfv[4];
#pragma unroll
      for (int i = 0; i < 4; ++i) {
        af[i]  = *(const bf16x8*)&sA[wr * 64 + i * 16 + (lane & 15)][kh * 32 + ((lane >> 4) * 8)];
        bfv[i] = *(const bf16x8*)&sB[wc * 64 + i * 16 + (lane & 15)][kh * 32 + ((lane >> 4) * 8)];
      }
#pragma unroll
      for (int mi = 0; mi < 4; ++mi)
#pragma unroll
        for (int ni = 0; ni < 4; ++ni)
          acc[mi][ni] = __builtin_amdgcn_mfma_f32_16x16x32_bf16(af[mi], bfv[ni], acc[mi][ni], 0, 0, 0);
    }
  }
#pragma unroll
  for (int mi = 0; mi < 4; ++mi) {
    int m = m0 + wr * 64 + mi * 16 + ((lane >> 4) * 4);
#pragma unroll
    for (int ni = 0; ni < 4; ++ni) {
      int n = n0 + wc * 64 + ni * 16 + (lane & 15);
#pragma unroll
      for (int i = 0; i < 4; ++i) C[(size_t)(m + i) * N + n] = acc[mi][ni][i];
    }
  }
}

// ---------------- sum 8 split-K partials: r0 = sum_z c01[z] ----------------
__global__ void k_reduce8(const float* __restrict__ c, float* __restrict__ r) {
  size_t i4 = ((size_t)blockIdx.x * 256 + threadIdx.x) * 4;
  float4 s = *(const float4*)(c + i4);
#pragma unroll
  for (int z = 1; z < 8; ++z) {
    float4 v = *(const float4*)(c + (size_t)z * 2048 * 1024 + i4);
    s.x += v.x; s.y += v.y; s.z += v.z; s.w += v.w;
  }
  *(float4*)(r + i4) = s;
}

// ---------------- per-column BN stats over batch (optionally summing two partials) ----------------
__global__ void k_stats_cols(const float* __restrict__ c0, const float* __restrict__ c1,
                             const float* __restrict__ g, const float* __restrict__ be,
                             float* __restrict__ scl, float* __restrict__ bia,
                             int rows, int cols) {
  int tid = threadIdx.x;
  int col = blockIdx.x * 64 + (tid & 63);
  int gq = tid >> 6;
  float s = 0.f, s2 = 0.f;
  for (int r = gq; r < rows; r += 4) {
    float v = c0[(size_t)r * cols + col];
    if (c1) v += c1[(size_t)r * cols + col];
    s += v;
    s2 = fmaf(v, v, s2);
  }
  __shared__ float red[2][256];
  red[0][tid] = s; red[1][tid] = s2;
  __syncthreads();
  if (tid < 64) {
    s  = red[0][tid] + red[0][tid + 64] + red[0][tid + 128] + red[0][tid + 192];
    s2 = red[1][tid] + red[1][tid + 64] + red[1][tid + 128] + red[1][tid + 192];
    float m = s / rows;
    float var = s2 / rows - m * m;
    float inv = rsqrtf(var + 1e-5f);
    scl[col] = g[col] * inv;
    bia[col] = be[col] - g[col] * inv * m;
  }
}

// ---------------- a1 = bf16(relu(r0*scl + bia)) ----------------
__global__ void k_applyA1(const float* __restrict__ c0,
                          const float* __restrict__ scl, const float* __restrict__ bia,
                          u16* __restrict__ a1) {
  size_t i4 = ((size_t)blockIdx.x * 256 + threadIdx.x) * 4;
  int n = (int)(i4 & 1023);
  float4 v0 = *(const float4*)(c0 + i4);
  ushort4 o;
  o.x = f2bf(fmaxf(fmaf(v0.x, scl[n + 0], bia[n + 0]), 0.f));
  o.y = f2bf(fmaxf(fmaf(v0.y, scl[n + 1], bia[n + 1]), 0.f));
  o.z = f2bf(fmaxf(fmaf(v0.z, scl[n + 2], bia[n + 2]), 0.f));
  o.w = f2bf(fmaxf(fmaf(v0.w, scl[n + 3], bia[n + 3]), 0.f));
  *(ushort4*)(a1 + i4) = o;
}

// ---------------- y[b] = out_b + sum_n relu((h0+h1)*scl+bia)*out_w[n] ----------------
__global__ void k_final(const float* __restrict__ h0, const float* __restrict__ h1b,
                        const float* __restrict__ scl, const float* __restrict__ bia,
                        const float* __restrict__ ow, const float* __restrict__ ob,
                        float* __restrict__ y) {
  int lane = threadIdx.x & 63, wid = threadIdx.x >> 6;
  int row = blockIdx.x * 4 + wid;
  const float* hr0 = h0 + (size_t)row * 1024;
  const float* hr1 = h1b + (size_t)row * 1024;
  float part = 0.f;
#pragma unroll
  for (int j = 0; j < 16; ++j) {
    int n = j * 64 + lane;
    float v = fmaf(hr0[n] + hr1[n], scl[n], bia[n]);
    v = fmaxf(v, 0.f);
    part = fmaf(v, ow[n], part);
  }
#pragma unroll
  for (int off = 32; off >= 1; off >>= 1) part += __shfl_xor(part, off);
  if (lane == 0) y[row] = part + ob[0];
}

extern "C" void kernel_launch(void* const* d_in, const int* in_sizes, int n_in,
                              void* d_out, int out_size, void* d_ws, size_t ws_size,
                              hipStream_t stream) {
  const int*   ids   = (const int*)d_in[0];
  const float* vals  = (const float*)d_in[1];
  const float* etab  = (const float*)d_in[2];
  const float* wb    = (const float*)d_in[3];
  const float* query = (const float*)d_in[4];
  const float* att   = (const float*)d_in[5];
  const float* bng   = (const float*)d_in[6];
  const float* bnb   = (const float*)d_in[7];
  const float* w0    = (const float*)d_in[8];
  const float* g0    = (const float*)d_in[10];
  const float* be0   = (const float*)d_in[11];
  const float* w1    = (const float*)d_in[12];
  const float* g1    = (const float*)d_in[14];
  const float* be1   = (const float*)d_in[15];
  const float* outw  = (const float*)d_in[16];
  const float* outb  = (const float*)d_in[17];
  float* y = (float*)d_out;

  // workspace layout (overlays keep peak at ~199.3 MB, same as last round):
  //   [0, 32K)            mt
  //   [32K, 33.59M)       w0bf (32MB)
  //   [33.59M, 35.68M)    w1bf (2MB)
  //   [35.68M, 102.79M)   tbuf (64MB bf16)   -- dead after k_applyA0
  //   [35.68M, 102.79M)   c01 (8x8MB f32)    -- overlays tbuf, written by gemm0
  //   [102.79M, 169.90M)  a0 (64MB bf16)     -- dead after gemm0
  //   [169.90M, 178.29M)  r0 (8MB f32)       -- overlays a0, written by reduce8
  //   [178.29M, 182.48M)  a1 (4MB bf16)
  //   [182.48M, 199.26M)  h1 partials (2x8MB f32)
  //   [199.26M, ...)      BN scale/bias scalars
  char* ws = (char*)d_ws;
  u16*   mt   = (u16*)(ws + 0);
  u16*   w0bf = (u16*)(ws + 32768ull);
  u16*   w1bf = (u16*)(ws + 33587200ull);
  u16*   tbuf = (u16*)(ws + 35684352ull);
  float* c01  = (float*)(ws + 35684352ull);
  u16*   a0   = (u16*)(ws + 102793216ull);
  float* r0   = (float*)(ws + 169902080ull);
  u16*   a1   = (u16*)(ws + 178290688ull);
  float* h1   = (float*)(ws + 182484992ull);
  float* sclA = (float*)(ws + 199262208ull);
  float* biaA = (float*)(ws + 199263232ull);
  float* scl1 = (float*)(ws + 199264256ull);
  float* bia1 = (float*)(ws + 199268352ull);
  float* scl2 = (float*)(ws + 199272448ull);
  float* bia2 = (float*)(ws + 199276544ull);

  k_prep_M<<<64, 256, 0, stream>>>(wb, query, mt);
  k_cvt<<<16384, 256, 0, stream>>>(w0, w0bf, 1024 * 16384);
  k_cvt<<<1024, 256, 0, stream>>>(w1, w1bf, 1024 * 1024);
  k_mega<<<dim3(2048, 4), 256, 0, stream>>>(ids, vals, etab, mt, att, tbuf);
  k_stats_o<<<256, 256, 0, stream>>>(tbuf, bng, bnb, sclA, biaA);
  k_applyA0<<<16384, 256, 0, stream>>>(tbuf, sclA, biaA, a0);
  // tbuf dead; gemm0 writes c01 over it. split-K=8 -> 1024 blocks = 4/CU.
  k_gemm<<<dim3(16, 8, 8), 256, 0, stream>>>(a0, w0bf, c01, 2048, 1024, 16384, 2048);
  // a0 dead; reduce into r0 (a0 region).
  k_reduce8<<<2048, 256, 0, stream>>>(c01, r0);
  k_stats_cols<<<16, 256, 0, stream>>>(r0, nullptr, g0, be0, scl1, bia1, 2048, 1024);
  k_applyA1<<<2048, 256, 0, stream>>>(r0, scl1, bia1, a1);
  // split-K=2 -> 256 blocks = 1/CU (was 0.5/CU).
  k_gemm<<<dim3(16, 8, 2), 256, 0, stream>>>(a1, w1bf, h1, 2048, 1024, 1024, 512);
  k_stats_cols<<<16, 256, 0, stream>>>(h1, h1 + 2048 * 1024, g1, be1, scl2, bia2, 2048, 1024);
  k_final<<<512, 256, 0, stream>>>(h1, h1 + 2048 * 1024, scl2, bia2, outw, outb, y);
}

// Round 3
// 826.385 us; speedup vs baseline: 1.3985x; 1.3490x over previous
//
#include <hip/hip_runtime.h>

typedef unsigned short u16;
typedef __attribute__((ext_vector_type(8))) short bf16x8;
typedef __attribute__((ext_vector_type(8))) unsigned short u16x8;
typedef __attribute__((ext_vector_type(4))) float f32x4;

__device__ __forceinline__ u16 f2bf(float f) {
  unsigned u = __builtin_bit_cast(unsigned, f);
  u += 0x7fffu + ((u >> 16) & 1u);
  return (u16)(u >> 16);
}
__device__ __forceinline__ float bf2f(u16 h) {
  unsigned u = ((unsigned)h) << 16;
  return __builtin_bit_cast(float, u);
}

#define NB 2048
#define NF 100
#define NE 64
#define NO 256
#define OCH 64
#define EMB_ST 68
#define EMBT_ST 136
#define G_ST 104
#define AW_ST 136
#define NIT 22

#define GLOAD16(gsrc, ldst)                                                        \
  __builtin_amdgcn_global_load_lds(                                                \
      (const __attribute__((address_space(1))) unsigned int*)(gsrc),               \
      (__attribute__((address_space(3))) unsigned int*)(ldst), 16, 0, 0)

// ---------------- prep: M[o][e] = 0.0625 * sum_k query[o,k]*Wb[k,e] ----------------
__global__ void k_prep_M(const float* __restrict__ wb, const float* __restrict__ q,
                         u16* __restrict__ mt) {
  int idx = blockIdx.x * 256 + threadIdx.x;   // 16384 = 256*64
  int o = idx >> 6, e = idx & 63;
  float s = 0.f;
  for (int k = 0; k < 64; ++k) s = fmaf(q[o * 64 + k], wb[k * 64 + e], s);
  mt[idx] = f2bf(s * 0.0625f);   // folds DK^-0.5 (0.125) and (alpha-1) (0.5)
}

// ---------------- f32 -> bf16 conversion ----------------
__global__ void k_cvt(const float* __restrict__ in, u16* __restrict__ out, int n) {
  int i4 = (blockIdx.x * 256 + threadIdx.x) * 4;
  if (i4 >= n) return;
  float4 v = *(const float4*)(in + i4);
  ushort4 o;
  o.x = f2bf(v.x); o.y = f2bf(v.y); o.z = f2bf(v.z); o.w = f2bf(v.w);
  *(ushort4*)(out + i4) = o;
}

// ------- fused gather + (per-o-chunk: gates GEMM + entmax + arm GEMM + expm1) -------
// One block per batch row; 4 o-chunks looped so the gather happens ONCE (was 4x).
__global__ __launch_bounds__(256) void k_mega(
    const int* __restrict__ ids, const float* __restrict__ vals,
    const float* __restrict__ etab, const u16* __restrict__ mt,
    const float* __restrict__ att, u16* __restrict__ tbuf) {
  __shared__ u16 s_emb[112][EMB_ST];     // [f][e], rows 100..111 zero
  __shared__ u16 s_embT[64][EMBT_ST];    // [e][f], cols 100..135 zero
  __shared__ u16 s_gates[64][G_ST];      // x = gates*(alpha-1), bf16
  __shared__ u16 s_aw[64][AW_ST];        // p_norm * att, cols 100..135 zero

  const int tid = threadIdx.x;
  const int lane = tid & 63;
  const int wid = tid >> 6;
  const int b = blockIdx.x;

  // phase 0: gather emb = emb_table[ids]*clip(v)  (once per b)
  for (int f = wid; f < NF; f += 4) {
    int id = ids[b * NF + f];
    float v = vals[b * NF + f];
    v = fminf(fmaxf(v, 0.001f), 1.0f);
    float ev = etab[(size_t)id * NE + lane] * v;
    u16 bf = f2bf(ev);
    s_emb[f][lane] = bf;
    s_embT[lane][f] = bf;
  }
  for (int i = tid; i < 12 * 64; i += 256) s_emb[100 + (i >> 6)][i & 63] = 0;
  for (int i = tid; i < 64 * 36; i += 256) s_embT[i / 36][100 + i % 36] = 0;
  __syncthreads();

  for (int oc = 0; oc < 4; ++oc) {
    const int obase = oc * OCH;
    // per-wave A fragments of M (o-tile = wid within chunk)
    bf16x8 amt[2];
#pragma unroll
    for (int kh = 0; kh < 2; ++kh)
      amt[kh] = *(const bf16x8*)(mt + ((obase + wid * 16 + (lane & 15)) * 64 +
                                       kh * 32 + ((lane >> 4) * 8)));

    // phase 1: gates[o][f] = M[o,:]·emb[f,:]  (K=64, 2 MFMA per f-tile)
#pragma unroll
    for (int ft = 0; ft < 7; ++ft) {
      f32x4 acc = {0.f, 0.f, 0.f, 0.f};
#pragma unroll
      for (int kh = 0; kh < 2; ++kh) {
        bf16x8 bfr = *(const bf16x8*)&s_emb[ft * 16 + (lane & 15)][kh * 32 + ((lane >> 4) * 8)];
        acc = __builtin_amdgcn_mfma_f32_16x16x32_bf16(amt[kh], bfr, acc, 0, 0, 0);
      }
      int fc = ft * 16 + (lane & 15);
      if (fc < NF) {
#pragma unroll
        for (int i = 0; i < 4; ++i)
          s_gates[wid * 16 + ((lane >> 4) * 4) + i][fc] = f2bf(acc[i]);
      }
    }
    __syncthreads();

    // phase 2: entmax (alpha=1.5) via bisection; quad (4 lanes) per o-row
    {
      const int q = tid & 3;
      const int r = tid >> 2;
      const int og = obase + r;
      float x[25];
#pragma unroll
      for (int j = 0; j < 25; ++j) x[j] = bf2f(s_gates[r][q * 25 + j]);
      float mx = x[0];
#pragma unroll
      for (int j = 1; j < 25; ++j) mx = fmaxf(mx, x[j]);
      mx = fmaxf(mx, __shfl_xor(mx, 1));
      mx = fmaxf(mx, __shfl_xor(mx, 2));
      float tau = mx - 1.0f, dm = 0.9f;   // tau_hi - tau_lo = 1 - (1/100)^0.5
      for (int it = 0; it < NIT; ++it) {
        dm *= 0.5f;
        float tm = tau + dm;
        float s = 0.f;
#pragma unroll
        for (int j = 0; j < 25; ++j) { float d = fmaxf(x[j] - tm, 0.f); s = fmaf(d, d, s); }
        s += __shfl_xor(s, 1);
        s += __shfl_xor(s, 2);
        if (s >= 1.0f) tau = tm;
      }
      float s = 0.f;
#pragma unroll
      for (int j = 0; j < 25; ++j) {
        float d = fmaxf(x[j] - tau, 0.f);
        float p = d * d;
        x[j] = p;
        s += p;
      }
      s += __shfl_xor(s, 1);
      s += __shfl_xor(s, 2);
      float rs = 1.0f / s;
#pragma unroll
      for (int j = 0; j < 25; ++j) {
        int f = q * 25 + j;
        s_aw[r][f] = f2bf(x[j] * rs * att[og * NF + f]);
      }
#pragma unroll
      for (int j = 0; j < 9; ++j) s_aw[r][100 + q * 9 + j] = 0;
    }
    __syncthreads();

    // phase 3: arm[o][e] = sum_f aw[o][f]*emb[f][e];  store t = expm1(arm)
    f32x4 acc[4] = {};
#pragma unroll
    for (int h = 0; h < 4; ++h) {
      bf16x8 afr = *(const bf16x8*)&s_aw[wid * 16 + (lane & 15)][h * 32 + ((lane >> 4) * 8)];
#pragma unroll
      for (int et = 0; et < 4; ++et) {
        bf16x8 bfr = *(const bf16x8*)&s_embT[et * 16 + (lane & 15)][h * 32 + ((lane >> 4) * 8)];
        acc[et] = __builtin_amdgcn_mfma_f32_16x16x32_bf16(afr, bfr, acc[et], 0, 0, 0);
      }
    }
    size_t orow = (size_t)b * NO + obase + wid * 16 + ((lane >> 4) * 4);
#pragma unroll
    for (int et = 0; et < 4; ++et) {
      int e = et * 16 + (lane & 15);
#pragma unroll
      for (int i = 0; i < 4; ++i)
        tbuf[(orow + i) * 64 + e] = f2bf(expm1f(acc[et][i]));
    }
    __syncthreads();   // protect s_gates/s_aw for next oc
  }
}

// ---------------- per-o BN stats over (b,e):  scl=g*inv, bia=be-g*inv*mean ----------------
__global__ void k_stats_o(const u16* __restrict__ t, const float* __restrict__ g,
                          const float* __restrict__ be, float* __restrict__ scl,
                          float* __restrict__ bia) {
  int tid = threadIdx.x;
  int o = blockIdx.x;
  int e = tid & 63, gq = tid >> 6;
  float s = 0.f, s2 = 0.f;
  for (int b = gq; b < NB; b += 4) {
    float v = bf2f(t[((size_t)b * NO + o) * 64 + e]);
    s += v;
    s2 = fmaf(v, v, s2);
  }
  __shared__ float red[2][256];
  red[0][tid] = s; red[1][tid] = s2;
  __syncthreads();
  for (int st = 128; st >= 1; st >>= 1) {
    if (tid < st) { red[0][tid] += red[0][tid + st]; red[1][tid] += red[1][tid + st]; }
    __syncthreads();
  }
  if (tid == 0) {
    float N = (float)(NB * 64);
    float m = red[0][0] / N;
    float var = red[1][0] / N - m * m;
    float inv = rsqrtf(var + 1e-5f);
    scl[o] = g[o] * inv;
    bia[o] = be[o] - g[o] * inv * m;
  }
}

// ---------------- apply arm-BN: a0 = bf16(t*scl[o] + bia[o]) ----------------
__global__ void k_applyA0(const u16* __restrict__ t, const float* __restrict__ scl,
                          const float* __restrict__ bia, u16* __restrict__ a0) {
  size_t i8 = ((size_t)blockIdx.x * 256 + threadIdx.x) * 8;
  int o = (int)((i8 >> 6) & 255);
  u16x8 tv = *(const u16x8*)(t + i8);
  float sc = scl[o], bi = bia[o];
  u16x8 ov;
#pragma unroll
  for (int j = 0; j < 8; ++j) ov[j] = f2bf(fmaf(bf2f(tv[j]), sc, bi));
  *(u16x8*)(a0 + i8) = ov;
}

// ---- bf16 GEMM, C[m][n] = sum_k A[m][k]*B[n][k] (B^T layout), split-K ----
// m97 structure: linear [128][64] LDS, global_load_lds width=16 staging,
// 2-barrier K-loop, 4 waves, 4x4 16x16x32 acc per wave.
__global__ __launch_bounds__(256) void k_gemm(const u16* __restrict__ A,
                                              const u16* __restrict__ B,
                                              float* __restrict__ C,
                                              int M, int N, int K, int ksz) {
  __shared__ u16 sA[128][64];
  __shared__ u16 sB[128][64];
  const int tid = threadIdx.x, lane = tid & 63, wid = tid >> 6;
  const int wr = wid >> 1, wc = wid & 1;
  const int m0 = blockIdx.x * 128, n0 = blockIdx.y * 128;
  const int k0 = blockIdx.z * ksz;
  C += (size_t)blockIdx.z * ((size_t)M * N);
  f32x4 acc[4][4];
#pragma unroll
  for (int mi = 0; mi < 4; ++mi)
#pragma unroll
    for (int ni = 0; ni < 4; ++ni) acc[mi][ni] = (f32x4){0.f, 0.f, 0.f, 0.f};

  // staging geometry: each wave fills rows [wid*32, wid*32+32) of sA and sB
  // via 4 global_load_lds each (1 KB per issue: 8 rows x 128 B).
  const int lrow = lane >> 3;    // 0..7
  const int lch = lane & 7;      // 16B chunk in row
  const u16* gA = A + (size_t)(m0 + wid * 32 + lrow) * K + k0 + lch * 8;
  const u16* gB = B + (size_t)(n0 + wid * 32 + lrow) * K + k0 + lch * 8;
  u16* lA = &sA[wid * 32][0];    // wave-uniform LDS base
  u16* lB = &sB[wid * 32][0];

  const int nkt = ksz / 64;
  for (int kt = 0; kt < nkt; ++kt) {
#pragma unroll
    for (int i = 0; i < 4; ++i) {
      GLOAD16(gA + (size_t)i * 8 * K, lA + i * 512);
      GLOAD16(gB + (size_t)i * 8 * K, lB + i * 512);
    }
    gA += 64; gB += 64;
    __syncthreads();   // vmcnt drain: tile staged
#pragma unroll
    for (int kh = 0; kh < 2; ++kh) {
      bf16x8 af[4], bfv[4];
#pragma unroll
      for (int i = 0; i < 4; ++i) {
        af[i]  = *(const bf16x8*)&sA[wr * 64 + i * 16 + (lane & 15)][kh * 32 + ((lane >> 4) * 8)];
        bfv[i] = *(const bf16x8*)&sB[wc * 64 + i * 16 + (lane & 15)][kh * 32 + ((lane >> 4) * 8)];
      }
#pragma unroll
      for (int mi = 0; mi < 4; ++mi)
#pragma unroll
        for (int ni = 0; ni < 4; ++ni)
          acc[mi][ni] = __builtin_amdgcn_mfma_f32_16x16x32_bf16(af[mi], bfv[ni], acc[mi][ni], 0, 0, 0);
    }
    __syncthreads();   // reads done before next-tile overwrite
  }
#pragma unroll
  for (int mi = 0; mi < 4; ++mi) {
    int m = m0 + wr * 64 + mi * 16 + ((lane >> 4) * 4);
#pragma unroll
    for (int ni = 0; ni < 4; ++ni) {
      int n = n0 + wc * 64 + ni * 16 + (lane & 15);
#pragma unroll
      for (int i = 0; i < 4; ++i) C[(size_t)(m + i) * N + n] = acc[mi][ni][i];
    }
  }
}

// ---------------- sum 8 split-K partials: r0 = sum_z c01[z] ----------------
__global__ void k_reduce8(const float* __restrict__ c, float* __restrict__ r) {
  size_t i4 = ((size_t)blockIdx.x * 256 + threadIdx.x) * 4;
  float4 s = *(const float4*)(c + i4);
#pragma unroll
  for (int z = 1; z < 8; ++z) {
    float4 v = *(const float4*)(c + (size_t)z * 2048 * 1024 + i4);
    s.x += v.x; s.y += v.y; s.z += v.z; s.w += v.w;
  }
  *(float4*)(r + i4) = s;
}

// ---------------- per-column BN stats over batch (optionally summing two partials) ----------------
__global__ void k_stats_cols(const float* __restrict__ c0, const float* __restrict__ c1,
                             const float* __restrict__ g, const float* __restrict__ be,
                             float* __restrict__ scl, float* __restrict__ bia,
                             int rows, int cols) {
  int tid = threadIdx.x;
  int col = blockIdx.x * 64 + (tid & 63);
  int gq = tid >> 6;
  float s = 0.f, s2 = 0.f;
  for (int r = gq; r < rows; r += 4) {
    float v = c0[(size_t)r * cols + col];
    if (c1) v += c1[(size_t)r * cols + col];
    s += v;
    s2 = fmaf(v, v, s2);
  }
  __shared__ float red[2][256];
  red[0][tid] = s; red[1][tid] = s2;
  __syncthreads();
  if (tid < 64) {
    s  = red[0][tid] + red[0][tid + 64] + red[0][tid + 128] + red[0][tid + 192];
    s2 = red[1][tid] + red[1][tid + 64] + red[1][tid + 128] + red[1][tid + 192];
    float m = s / rows;
    float var = s2 / rows - m * m;
    float inv = rsqrtf(var + 1e-5f);
    scl[col] = g[col] * inv;
    bia[col] = be[col] - g[col] * inv * m;
  }
}

// ---------------- a1 = bf16(relu(r0*scl + bia)) ----------------
__global__ void k_applyA1(const float* __restrict__ c0,
                          const float* __restrict__ scl, const float* __restrict__ bia,
                          u16* __restrict__ a1) {
  size_t i4 = ((size_t)blockIdx.x * 256 + threadIdx.x) * 4;
  int n = (int)(i4 & 1023);
  float4 v0 = *(const float4*)(c0 + i4);
  ushort4 o;
  o.x = f2bf(fmaxf(fmaf(v0.x, scl[n + 0], bia[n + 0]), 0.f));
  o.y = f2bf(fmaxf(fmaf(v0.y, scl[n + 1], bia[n + 1]), 0.f));
  o.z = f2bf(fmaxf(fmaf(v0.z, scl[n + 2], bia[n + 2]), 0.f));
  o.w = f2bf(fmaxf(fmaf(v0.w, scl[n + 3], bia[n + 3]), 0.f));
  *(ushort4*)(a1 + i4) = o;
}

// ---------------- y[b] = out_b + sum_n relu((h0+h1)*scl+bia)*out_w[n] ----------------
__global__ void k_final(const float* __restrict__ h0, const float* __restrict__ h1b,
                        const float* __restrict__ scl, const float* __restrict__ bia,
                        const float* __restrict__ ow, const float* __restrict__ ob,
                        float* __restrict__ y) {
  int lane = threadIdx.x & 63, wid = threadIdx.x >> 6;
  int row = blockIdx.x * 4 + wid;
  const float* hr0 = h0 + (size_t)row * 1024;
  const float* hr1 = h1b + (size_t)row * 1024;
  float part = 0.f;
#pragma unroll
  for (int j = 0; j < 16; ++j) {
    int n = j * 64 + lane;
    float v = fmaf(hr0[n] + hr1[n], scl[n], bia[n]);
    v = fmaxf(v, 0.f);
    part = fmaf(v, ow[n], part);
  }
#pragma unroll
  for (int off = 32; off >= 1; off >>= 1) part += __shfl_xor(part, off);
  if (lane == 0) y[row] = part + ob[0];
}

extern "C" void kernel_launch(void* const* d_in, const int* in_sizes, int n_in,
                              void* d_out, int out_size, void* d_ws, size_t ws_size,
                              hipStream_t stream) {
  const int*   ids   = (const int*)d_in[0];
  const float* vals  = (const float*)d_in[1];
  const float* etab  = (const float*)d_in[2];
  const float* wb    = (const float*)d_in[3];
  const float* query = (const float*)d_in[4];
  const float* att   = (const float*)d_in[5];
  const float* bng   = (const float*)d_in[6];
  const float* bnb   = (const float*)d_in[7];
  const float* w0    = (const float*)d_in[8];
  const float* g0    = (const float*)d_in[10];
  const float* be0   = (const float*)d_in[11];
  const float* w1    = (const float*)d_in[12];
  const float* g1    = (const float*)d_in[14];
  const float* be1   = (const float*)d_in[15];
  const float* outw  = (const float*)d_in[16];
  const float* outb  = (const float*)d_in[17];
  float* y = (float*)d_out;

  // workspace layout (overlays; peak ~199.3 MB):
  //   [0, 32K)            mt
  //   [32K, 33.59M)       w0bf (32MB)
  //   [33.59M, 35.68M)    w1bf (2MB)
  //   [35.68M, 102.79M)   tbuf (64MB bf16)   -- dead after k_applyA0
  //   [35.68M, 102.79M)   c01 (8x8MB f32)    -- overlays tbuf, written by gemm0
  //   [102.79M, 169.90M)  a0 (64MB bf16)     -- dead after gemm0
  //   [169.90M, 178.29M)  r0 (8MB f32)       -- overlays a0's tail region
  //   [178.29M, 182.48M)  a1 (4MB bf16)
  //   [182.48M, 199.26M)  h1 partials (2x8MB f32)
  //   [199.26M, ...)      BN scale/bias scalars
  char* ws = (char*)d_ws;
  u16*   mt   = (u16*)(ws + 0);
  u16*   w0bf = (u16*)(ws + 32768ull);
  u16*   w1bf = (u16*)(ws + 33587200ull);
  u16*   tbuf = (u16*)(ws + 35684352ull);
  float* c01  = (float*)(ws + 35684352ull);
  u16*   a0   = (u16*)(ws + 102793216ull);
  float* r0   = (float*)(ws + 169902080ull);
  u16*   a1   = (u16*)(ws + 178290688ull);
  float* h1   = (float*)(ws + 182484992ull);
  float* sclA = (float*)(ws + 199262208ull);
  float* biaA = (float*)(ws + 199263232ull);
  float* scl1 = (float*)(ws + 199264256ull);
  float* bia1 = (float*)(ws + 199268352ull);
  float* scl2 = (float*)(ws + 199272448ull);
  float* bia2 = (float*)(ws + 199276544ull);

  k_prep_M<<<64, 256, 0, stream>>>(wb, query, mt);
  k_cvt<<<16384, 256, 0, stream>>>(w0, w0bf, 1024 * 16384);
  k_cvt<<<1024, 256, 0, stream>>>(w1, w1bf, 1024 * 1024);
  k_mega<<<2048, 256, 0, stream>>>(ids, vals, etab, mt, att, tbuf);
  k_stats_o<<<256, 256, 0, stream>>>(tbuf, bng, bnb, sclA, biaA);
  k_applyA0<<<16384, 256, 0, stream>>>(tbuf, sclA, biaA, a0);
  // tbuf dead; gemm0 writes c01 over it. split-K=8 -> 1024 blocks = 4/CU.
  k_gemm<<<dim3(16, 8, 8), 256, 0, stream>>>(a0, w0bf, c01, 2048, 1024, 16384, 2048);
  // a0 dead; reduce into r0.
  k_reduce8<<<2048, 256, 0, stream>>>(c01, r0);
  k_stats_cols<<<16, 256, 0, stream>>>(r0, nullptr, g0, be0, scl1, bia1, 2048, 1024);
  k_applyA1<<<2048, 256, 0, stream>>>(r0, scl1, bia1, a1);
  k_gemm<<<dim3(16, 8, 2), 256, 0, stream>>>(a1, w1bf, h1, 2048, 1024, 1024, 512);
  k_stats_cols<<<16, 256, 0, stream>>>(h1, h1 + 2048 * 1024, g1, be1, scl2, bia2, 2048, 1024);
  k_final<<<512, 256, 0, stream>>>(h1, h1 + 2048 * 1024, scl2, bia2, outw, outb, y);
}